// Round 1
// baseline (242.460 us; speedup 1.0000x reference)
//
#include <hip/hip_runtime.h>
#include <stdint.h>
#include <stddef.h>

// Problem constants (from reference)
constexpr int kNodes = 50000;
constexpr int kEdges = 500000;
constexpr int kD     = 128;   // per-half feature dim
constexpr int kC     = 64;    // out classes
constexpr int kK     = 256;   // total K = 2*kD

typedef __attribute__((ext_vector_type(8))) short  short8;   // 8 x bf16 (4 VGPRs)
typedef __attribute__((ext_vector_type(4))) float  floatx4;  // MFMA C/D

// fp32 -> bf16, round-to-nearest-even (bit trick; inputs are finite gaussians)
__device__ __forceinline__ unsigned short f2bf(float f) {
  union { float f; unsigned u; } v; v.f = f;
  unsigned u = v.u;
  unsigned r = u + 0x7FFFu + ((u >> 16) & 1u);
  return (unsigned short)(r >> 16);
}

__device__ __forceinline__ short8 cvt8(float4 a, float4 b) {
  short8 r;
  r[0] = (short)f2bf(a.x); r[1] = (short)f2bf(a.y);
  r[2] = (short)f2bf(a.z); r[3] = (short)f2bf(a.w);
  r[4] = (short)f2bf(b.x); r[5] = (short)f2bf(b.y);
  r[6] = (short)f2bf(b.z); r[7] = (short)f2bf(b.w);
  return r;
}

// Kernel 1: convert h (fp32, 50000x128) -> bf16 in workspace.
// Halves gather traffic and makes A-fragment loads a single dwordx4.
__global__ void cvt_h_kernel(const float* __restrict__ h,
                             unsigned short* __restrict__ hb) {
  constexpr int n4 = kNodes * kD / 4;  // 1.6M float4s
  int stride = gridDim.x * blockDim.x;
  for (int i = blockIdx.x * blockDim.x + threadIdx.x; i < n4; i += stride) {
    float4 v = reinterpret_cast<const float4*>(h)[i];
    ushort4 o;
    o.x = f2bf(v.x); o.y = f2bf(v.y); o.z = f2bf(v.z); o.w = f2bf(v.w);
    reinterpret_cast<ushort4*>(hb)[i] = o;
  }
}

// Main kernel: block = 256 threads = 4 waves; each wave computes a 16-edge x
// 64-class tile via mfma_f32_16x16x32_bf16 (4 N-tiles x 8 K-steps).
//
// B (= W^T, 256x64) is staged once per block into LDS, PRE-SWIZZLED into
// MFMA B-fragment order: fragment (kstep,ntile,lane) holds
// B[kstep*32 + (lane>>4)*8 + j][ntile*16 + (lane&15)] = W[n][k+j], j=0..7,
// which is 8 contiguous fp32 in W -> stage with two float4 loads, read back
// in the hot loop with a single ds_read_b128 per fragment.
template <bool BF16H>
__global__ __launch_bounds__(256, 4)
void edge_mlp_kernel(const unsigned short* __restrict__ hb,
                     const float* __restrict__ hf,
                     const int* __restrict__ src,
                     const int* __restrict__ dst,
                     const float* __restrict__ W,
                     const float* __restrict__ b,
                     float* __restrict__ out) {
  __shared__ short8 Blds[8 * 4 * 64];  // 2048 fragments * 16B = 32 KiB

  const int tid = threadIdx.x;

  // ---- Stage W -> LDS in B-fragment order (8 slots per thread) ----
  for (int s = tid; s < 2048; s += 256) {
    int kstep = s >> 8;          // 0..7
    int rem   = s & 255;
    int ntile = rem >> 6;        // 0..3
    int ln    = rem & 63;        // lane this fragment belongs to
    int n = ntile * 16 + (ln & 15);
    int k = kstep * 32 + (ln >> 4) * 8;
    const float* wp = W + n * kK + k;
    float4 w0 = *reinterpret_cast<const float4*>(wp);
    float4 w1 = *reinterpret_cast<const float4*>(wp + 4);
    Blds[s] = cvt8(w0, w1);
  }

  const int lane = tid & 63;
  const int wave = tid >> 6;
  const int rowA = lane & 15;   // edge within wave tile (A operand row)
  const int quad = lane >> 4;   // selects K sub-segment / output row group

  const long ebase = (long)blockIdx.x * 64 + (long)wave * 16;
  const long eA    = ebase + rowA;
  const int  ec    = (eA < kEdges) ? (int)eA : (kEdges - 1);  // clamp tail reads
  const int  si    = src[ec];
  const int  di    = dst[ec];

  // ---- Preload all 8 A-fragments (independent of LDS; hides latency) ----
  short8 afrag[8];
  if (BF16H) {
    const unsigned short* ps = hb + (size_t)si * kD;
    const unsigned short* pd = hb + (size_t)di * kD;
#pragma unroll
    for (int kstep = 0; kstep < 8; ++kstep) {
      int koff = kstep * 32 + quad * 8;
      const unsigned short* ap = (kstep < 4) ? (ps + koff) : (pd + (koff - kD));
      afrag[kstep] = *reinterpret_cast<const short8*>(ap);  // 16B aligned
    }
  } else {
    const float* ps = hf + (size_t)si * kD;
    const float* pd = hf + (size_t)di * kD;
#pragma unroll
    for (int kstep = 0; kstep < 8; ++kstep) {
      int koff = kstep * 32 + quad * 8;
      const float* ap = (kstep < 4) ? (ps + koff) : (pd + (koff - kD));
      float4 v0 = *reinterpret_cast<const float4*>(ap);
      float4 v1 = *reinterpret_cast<const float4*>(ap + 4);
      afrag[kstep] = cvt8(v0, v1);
    }
  }

  floatx4 acc[4];
#pragma unroll
  for (int nt = 0; nt < 4; ++nt) acc[nt] = (floatx4){0.f, 0.f, 0.f, 0.f};

  __syncthreads();

  // ---- Hot loop: 32 MFMAs, B fragments via ds_read_b128 ----
#pragma unroll
  for (int kstep = 0; kstep < 8; ++kstep) {
#pragma unroll
    for (int nt = 0; nt < 4; ++nt) {
      short8 bfrag = Blds[(kstep * 4 + nt) * 64 + lane];
      acc[nt] = __builtin_amdgcn_mfma_f32_16x16x32_bf16(afrag[kstep], bfrag,
                                                        acc[nt], 0, 0, 0);
    }
  }

  // ---- Epilogue: C/D layout col=lane&15, row=quad*4+reg  [m89/m91] ----
  const int col = lane & 15;
#pragma unroll
  for (int nt = 0; nt < 4; ++nt) {
    float bv = b[nt * 16 + col];
#pragma unroll
    for (int r = 0; r < 4; ++r) {
      long orow = ebase + quad * 4 + r;
      if (orow < kEdges) {
        out[orow * (long)kC + nt * 16 + col] = acc[nt][r] + bv;
      }
    }
  }
}

extern "C" void kernel_launch(void* const* d_in, const int* in_sizes, int n_in,
                              void* d_out, int out_size, void* d_ws, size_t ws_size,
                              hipStream_t stream) {
  const float* h   = (const float*)d_in[0];
  const int*   src = (const int*)  d_in[1];
  const int*   dst = (const int*)  d_in[2];
  const float* W   = (const float*)d_in[3];
  const float* b   = (const float*)d_in[4];
  float*       out = (float*)d_out;

  const int grid = (kEdges + 63) / 64;  // 7813 blocks
  const size_t need = (size_t)kNodes * kD * sizeof(unsigned short);  // 12.8 MB

  if (ws_size >= need) {
    unsigned short* hb = (unsigned short*)d_ws;
    cvt_h_kernel<<<1024, 256, 0, stream>>>(h, hb);
    edge_mlp_kernel<true><<<grid, 256, 0, stream>>>(hb, h, src, dst, W, b, out);
  } else {
    // Workspace too small: gather fp32 h directly (2x gather bytes, still correct)
    edge_mlp_kernel<false><<<grid, 256, 0, stream>>>(nullptr, h, src, dst, W, b, out);
  }
}